// Round 3
// baseline (337.930 us; speedup 1.0000x reference)
//
#include <hip/hip_runtime.h>
#include <hip/hip_bf16.h>

typedef __attribute__((ext_vector_type(8))) short bf16x8;
typedef __attribute__((ext_vector_type(4))) float f32x4;

#define GLOAD_LDS16(gptr, lptr) \
  __builtin_amdgcn_global_load_lds((const __attribute__((address_space(1))) void*)(gptr), \
                                   (__attribute__((address_space(3))) void*)(lptr), 16, 0, 0)

__device__ __forceinline__ unsigned short f2b(float f) {
  union { float f; unsigned u; } x; x.f = f;
  unsigned r = x.u + 0x7fffu + ((x.u >> 16) & 1u);
  return (unsigned short)(r >> 16);
}
__device__ __forceinline__ float b2f(unsigned short u) {
  union { unsigned u; float f; } x; x.u = ((unsigned)u) << 16;
  return x.f;
}

// ---------------- fp32 -> bf16 cast ----------------
__global__ void cast_kernel(const float* __restrict__ in, unsigned short* __restrict__ out, int n) {
  const int i = (blockIdx.x * 256 + threadIdx.x) * 4;
  if (i < n) {
    const float4 v = *(const float4*)(in + i);
    ushort4 r;
    r.x = f2b(v.x); r.y = f2b(v.y); r.z = f2b(v.z); r.w = f2b(v.w);
    *(ushort4*)(out + i) = r;
  }
}

// ---------------- GEMM 256x256 tile, BK=32, 4-deep pipeline, 8 waves ----------------
// C[M][N] = A[M][K] * Bm[N][K]^T + bias.  Counted-vmcnt schedule (T3+T4), LDS XOR
// swizzle (T2, involution a^=((a>>7)&3)<<4), setprio (T5), XCD block swizzle (T1).
template<int OUTF32>
__global__ __launch_bounds__(512, 2)
void gemm256(const unsigned short* __restrict__ A,
             const unsigned short* __restrict__ Bm,
             const float* __restrict__ bias,
             void* __restrict__ Cp,
             int M, int N, int K)
{
  __shared__ __align__(16) char Lds[131072];   // 4 bufs x (A 16KB + B 16KB)
  const int t  = threadIdx.x;
  const int l  = t & 63;
  const int w  = t >> 6;
  const int lr = l & 15;
  const int lkb = (l >> 4) << 4;    // k-chunk byte offset 0/16/32/48
  const int wr = w >> 2;            // 0..1  (M half)
  const int wc = w & 3;             // 0..3  (N quarter)

  // XCD-aware block swizzle (grid % 8 == 0 for all our shapes)
  const int nwg = gridDim.x;
  const int wg  = (blockIdx.x & 7) * (nwg >> 3) + (blockIdx.x >> 3);
  const int NBN = N >> 8;
  const int bm = wg / NBN, bn = wg % NBN;

  // swizzled read offsets within a 16KB A/B region
  int aoff[8], boff[4];
#pragma unroll
  for (int mi = 0; mi < 8; ++mi) {
    int a = ((wr * 128 + mi * 16 + lr) << 6) | lkb;
    aoff[mi] = a ^ (((a >> 7) & 3) << 4);
  }
#pragma unroll
  for (int ni = 0; ni < 4; ++ni) {
    int a = ((wc * 64 + ni * 16 + lr) << 6) | lkb;
    boff[ni] = a ^ (((a >> 7) & 3) << 4);
  }

  // staging: lane's linear LDS dests lb0, lb1; source element = swz(lb) (involution)
  const int lb0 = t << 4, lb1 = lb0 + 8192;
  const int s0 = lb0 ^ (((lb0 >> 7) & 3) << 4);
  const int s1 = lb1 ^ (((lb1 >> 7) & 3) << 4);
  const long K2 = (long)K * 2;
  const char* Ab = (const char*)A  + (long)(bm * 256) * K2;
  const char* Bb = (const char*)Bm + (long)(bn * 256) * K2;
  const char* asrc0 = Ab + (long)(s0 >> 6) * K2 + (s0 & 63);
  const char* asrc1 = Ab + (long)(s1 >> 6) * K2 + (s1 & 63);
  const char* bsrc0 = Bb + (long)(s0 >> 6) * K2 + (s0 & 63);
  const char* bsrc1 = Bb + (long)(s1 >> 6) * K2 + (s1 & 63);

  f32x4 acc[8][4] = {};
  const int nt = K >> 5;

  // prologue: stage tiles 0,1,2
#pragma unroll
  for (int pt = 0; pt < 3; ++pt) {
    char* SD = Lds + pt * 32768;
    const long kb = (long)pt << 6;
    GLOAD_LDS16(asrc0 + kb, SD + lb0);
    GLOAD_LDS16(asrc1 + kb, SD + lb1);
    GLOAD_LDS16(bsrc0 + kb, SD + 16384 + lb0);
    GLOAD_LDS16(bsrc1 + kb, SD + 16384 + lb1);
  }
  asm volatile("s_waitcnt vmcnt(8)" ::: "memory");
  __builtin_amdgcn_s_barrier();

  for (int tt = 0; tt < nt; ++tt) {
    const char* LA = Lds + (tt & 3) * 32768;
    const char* LB = LA + 16384;
    const int ts = tt + 3;
    char* SD = Lds + (ts & 3) * 32768;
    const long kb = (long)ts << 6;
    const bool st = (ts < nt);

    // ---- phase A: B-frags + A-frags mi0-3; stage A(ts) ----
    bf16x8 bfr[4], af[4];
#pragma unroll
    for (int ni = 0; ni < 4; ++ni) bfr[ni] = *(const bf16x8*)(LB + boff[ni]);
#pragma unroll
    for (int mi = 0; mi < 4; ++mi) af[mi] = *(const bf16x8*)(LA + aoff[mi]);
    if (st) {
      GLOAD_LDS16(asrc0 + kb, SD + lb0);
      GLOAD_LDS16(asrc1 + kb, SD + lb1);
    }
    __builtin_amdgcn_s_barrier();
    __builtin_amdgcn_s_setprio(1);
#pragma unroll
    for (int mi = 0; mi < 4; ++mi)
#pragma unroll
      for (int ni = 0; ni < 4; ++ni)
        acc[mi][ni] = __builtin_amdgcn_mfma_f32_16x16x32_bf16(af[mi], bfr[ni], acc[mi][ni], 0, 0, 0);
    __builtin_amdgcn_s_setprio(0);
    __builtin_amdgcn_s_barrier();

    // ---- phase B: A-frags mi4-7; stage B(ts) ----
#pragma unroll
    for (int mi = 0; mi < 4; ++mi) af[mi] = *(const bf16x8*)(LA + aoff[mi + 4]);
    if (st) {
      GLOAD_LDS16(bsrc0 + kb, SD + 16384 + lb0);
      GLOAD_LDS16(bsrc1 + kb, SD + 16384 + lb1);
    }
    __builtin_amdgcn_s_barrier();
    __builtin_amdgcn_s_setprio(1);
#pragma unroll
    for (int mi = 0; mi < 4; ++mi)
#pragma unroll
      for (int ni = 0; ni < 4; ++ni)
        acc[mi + 4][ni] = __builtin_amdgcn_mfma_f32_16x16x32_bf16(af[mi], bfr[ni], acc[mi + 4][ni], 0, 0, 0);
    __builtin_amdgcn_s_setprio(0);
    // counted drain: keep 2 tiles (8 loads) in flight; epilogue 8 -> 4 -> 0
    if (tt < nt - 3)       asm volatile("s_waitcnt vmcnt(8)" ::: "memory");
    else if (tt == nt - 3) asm volatile("s_waitcnt vmcnt(4)" ::: "memory");
    else if (tt == nt - 2) asm volatile("s_waitcnt vmcnt(0)" ::: "memory");
    __builtin_amdgcn_s_barrier();
  }

  // epilogue: C += bias, write (C/D layout: col=lane&15, row=(lane>>4)*4+reg)
  const int roff = (l >> 4) << 2;
  const int row0 = bm * 256 + wr * 128 + roff;
  const int col0 = bn * 256 + wc * 64 + lr;
#pragma unroll
  for (int ni = 0; ni < 4; ++ni) {
    const int col = col0 + ni * 16;
    const float bv = bias ? bias[col] : 0.0f;
#pragma unroll
    for (int mi = 0; mi < 8; ++mi) {
#pragma unroll
      for (int r = 0; r < 4; ++r) {
        const int row = row0 + mi * 16 + r;
        const float v = acc[mi][ni][r] + bv;
        if (OUTF32) ((float*)Cp)[(long)row * N + col] = v;
        else ((unsigned short*)Cp)[(long)row * N + col] = f2b(v);
      }
    }
  }
}

// ---------------- RoPE: qkv[B][T][3][H*128] -> Qr,Kr (B,H,T,D) bf16 ----------------
__global__ void rope_kernel(const unsigned short* __restrict__ qkv,
                            unsigned short* __restrict__ Qr,
                            unsigned short* __restrict__ Kr)
{
  const int T = 2048;
  const int idx = blockIdx.x * 256 + threadIdx.x;   // [bh(5) | t(11) | d(6)]
  const int d  = idx & 63;
  const int tt = (idx >> 6) & (T - 1);
  const int bh = idx >> 17;
  const int b = bh >> 4, h = bh & 15;
  const long base = ((long)(b * T + tt) * 3) * 2048 + h * 128;
  const float inv = exp2f(-(float)d * 0.2076205059304602f);
  const float fr = (float)tt * inv;
  float sn, cs;
  sincosf(fr, &sn, &cs);
  const float q1 = b2f(qkv[base + 2 * d]);
  const float q2 = b2f(qkv[base + 2 * d + 1]);
  const float k1 = b2f(qkv[base + 2048 + 2 * d]);
  const float k2 = b2f(qkv[base + 2048 + 2 * d + 1]);
  const long ob = ((long)bh * T + tt) * 128;
  Qr[ob + d]      = f2b(q1 * cs - q2 * sn);
  Qr[ob + 64 + d] = f2b(q1 * sn + q2 * cs);
  Kr[ob + d]      = f2b(k1 * cs - k2 * sn);
  Kr[ob + 64 + d] = f2b(k1 * sn + k2 * cs);
}

// ---------------- V transpose: qkv(...,s=2,...) -> Vt (B,H,D,T) bf16 ----------------
__global__ void vtrans_kernel(const unsigned short* __restrict__ qkv,
                              unsigned short* __restrict__ Vt)
{
  const int T = 2048;
  __shared__ unsigned short ld[128][65];
  const int bh = blockIdx.y, tt = blockIdx.x;
  const int b = bh >> 4, h = bh & 15;
  const int t = threadIdx.x;
#pragma unroll
  for (int i = 0; i < 32; ++i) {
    const int idx = i * 256 + t;
    const int d = idx & 127, tr = idx >> 7;
    ld[d][tr] = qkv[((long)(b * T + tt * 64 + tr) * 3 + 2) * 2048 + h * 128 + d];
  }
  __syncthreads();
#pragma unroll
  for (int i = 0; i < 32; ++i) {
    const int idx = i * 256 + t;
    const int tc = idx & 63, dr = idx >> 6;
    Vt[((long)bh * 128 + dr) * T + tt * 64 + tc] = ld[dr][tc];
  }
}

// ---------------- causal flash attention ----------------
__global__ __launch_bounds__(256)
void attn_fwd(const unsigned short* __restrict__ Q,
              const unsigned short* __restrict__ Kg,
              const unsigned short* __restrict__ Vt,
              unsigned short* __restrict__ O, int T)
{
  __shared__ __align__(16) unsigned short Ks[2][64 * 128];
  __shared__ __align__(16) unsigned short Vs[2][128 * 64];
  __shared__ __align__(16) unsigned short Ps[4][16 * 64];
  const int t = threadIdx.x;
  const int w = t >> 6, l = t & 63;
  const int lr = l & 15;
  const int g16 = (l >> 4) << 4;
  const int sw = (lr & 7) << 4;
  const int bh = blockIdx.x;
  const int qt = (gridDim.y - 1) - blockIdx.y;
  const int q0 = qt * 64 + w * 16;
  const long hbase = (long)bh * T * 128;
  const long hbase2 = hbase * 2;
  const long T2 = (long)T * 2;
  const int roff = (l >> 4) << 2;

  bf16x8 qf[4];
  const unsigned short* Qrow = Q + hbase + (long)(q0 + lr) * 128;
#pragma unroll
  for (int ds = 0; ds < 4; ++ds) qf[ds] = *(const bf16x8*)&Qrow[ds * 32 + (g16 >> 1)];

  f32x4 o[8] = {};
  float m[4]    = {-INFINITY, -INFINITY, -INFINITY, -INFINITY};
  float lsum[4] = {0.f, 0.f, 0.f, 0.f};

  auto stage = [&](int kt, int buf) {
#pragma unroll
    for (int c = 0; c < 4; ++c) {
      const int o2 = t * 16 + c * 4096;
      const int krow = o2 >> 8, kcb = o2 & 255;
      GLOAD_LDS16((const char*)Kg + hbase2 + (long)kt * 16384 + krow * 256 + (kcb ^ ((krow & 7) << 4)),
                  (char*)Ks[buf] + o2);
      const int vrow = o2 >> 7, vcb = o2 & 127;
      GLOAD_LDS16((const char*)Vt + (long)(bh * 128 + vrow) * T2 + (long)kt * 128 + (vcb ^ ((vrow & 7) << 4)),
                  (char*)Vs[buf] + o2);
    }
  };

  const int ntile = qt + 1;
  stage(0, 0);
  __syncthreads();

  for (int kt = 0; kt < ntile; ++kt) {
    const int cur = kt & 1;
    if (kt + 1 < ntile) stage(kt + 1, cur ^ 1);

    const char* KsB = (const char*)Ks[cur];
    const char* VsB = (const char*)Vs[cur];

    f32x4 s[4] = {};
    __builtin_amdgcn_s_setprio(1);
#pragma unroll
    for (int tj = 0; tj < 4; ++tj)
#pragma unroll
      for (int ds = 0; ds < 4; ++ds) {
        bf16x8 kf = *(const bf16x8*)(KsB + (tj * 16 + lr) * 256 + ((ds * 64 + g16) ^ sw));
        s[tj] = __builtin_amdgcn_mfma_f32_16x16x32_bf16(qf[ds], kf, s[tj], 0, 0, 0);
      }
    __builtin_amdgcn_s_setprio(0);

    const float scale = 0.08838834764831845f;
#pragma unroll
    for (int tj = 0; tj < 4; ++tj) s[tj] *= scale;
    if (kt == qt) {
#pragma unroll
      for (int tj = 0; tj < 4; ++tj)
#pragma unroll
        for (int j = 0; j < 4; ++j)
          if (kt * 64 + tj * 16 + lr > q0 + roff + j) s[tj][j] = -INFINITY;
    }

    float corr[4];
#pragma unroll
    for (int j = 0; j < 4; ++j) {
      float v = fmaxf(fmaxf(s[0][j], s[1][j]), fmaxf(s[2][j], s[3][j]));
      v = fmaxf(v, __shfl_xor(v, 1, 64));
      v = fmaxf(v, __shfl_xor(v, 2, 64));
      v = fmaxf(v, __shfl_xor(v, 4, 64));
      v = fmaxf(v, __shfl_xor(v, 8, 64));
      const float mn = fmaxf(m[j], v);
      corr[j] = __expf(m[j] - mn);
      m[j] = mn;
    }
    float rs[4] = {0.f, 0.f, 0.f, 0.f};
#pragma unroll
    for (int tj = 0; tj < 4; ++tj)
#pragma unroll
      for (int j = 0; j < 4; ++j) {
        const float p = __expf(s[tj][j] - m[j]);
        rs[j] += p;
        const int prow = roff + j;
        *(unsigned short*)((char*)Ps[w] + prow * 128 + (((tj * 16 + lr) * 2) ^ ((prow & 7) << 4))) = f2b(p);
      }
#pragma unroll
    for (int j = 0; j < 4; ++j) {
      float v = rs[j];
      v += __shfl_xor(v, 1, 64);
      v += __shfl_xor(v, 2, 64);
      v += __shfl_xor(v, 4, 64);
      v += __shfl_xor(v, 8, 64);
      lsum[j] = lsum[j] * corr[j] + v;
    }
#pragma unroll
    for (int nj = 0; nj < 8; ++nj)
#pragma unroll
      for (int j = 0; j < 4; ++j) o[nj][j] *= corr[j];

    __builtin_amdgcn_s_setprio(1);
#pragma unroll
    for (int ks = 0; ks < 2; ++ks) {
      bf16x8 pf = *(const bf16x8*)((const char*)Ps[w] + lr * 128 + ((ks * 64 + g16) ^ sw));
#pragma unroll
      for (int nj = 0; nj < 8; ++nj) {
        bf16x8 vf = *(const bf16x8*)(VsB + (nj * 16 + lr) * 128 + ((ks * 64 + g16) ^ sw));
        o[nj] = __builtin_amdgcn_mfma_f32_16x16x32_bf16(pf, vf, o[nj], 0, 0, 0);
      }
    }
    __builtin_amdgcn_s_setprio(0);
    __syncthreads();
  }

  float inv[4];
#pragma unroll
  for (int j = 0; j < 4; ++j) inv[j] = 1.0f / lsum[j];
  const int b = bh >> 4, h = bh & 15;
#pragma unroll
  for (int nj = 0; nj < 8; ++nj)
#pragma unroll
    for (int j = 0; j < 4; ++j) {
      const int q = q0 + roff + j;
      const int d = nj * 16 + lr;
      O[(long)(b * T + q) * 2048 + h * 128 + d] = f2b(o[nj][j] * inv[j]);
    }
}

// ---------------- launch ----------------
extern "C" void kernel_launch(void* const* d_in, const int* in_sizes, int n_in,
                              void* d_out, int out_size, void* d_ws, size_t ws_size,
                              hipStream_t stream)
{
  const int B = 2, T = 2048, C = 2048;
  const int M = B * T;        // 4096
  const int N1 = 3 * C;       // 6144
  const float* x    = (const float*)d_in[0];
  const float* Wqkv = (const float*)d_in[1];
  const float* bqkv = (const float*)d_in[2];
  const float* Wout = (const float*)d_in[3];
  const float* bout = (const float*)d_in[4];
  float* out = (float*)d_out;

  char* p = (char*)d_ws;
  unsigned short* xb    = (unsigned short*)p; p += (size_t)M * C * 2;
  unsigned short* wqkvb = (unsigned short*)p; p += (size_t)N1 * C * 2;
  unsigned short* woutb = (unsigned short*)p; p += (size_t)C * C * 2;
  unsigned short* qkv   = (unsigned short*)p; p += (size_t)M * N1 * 2;
  unsigned short* Qr    = (unsigned short*)p; p += (size_t)M * C * 2;
  unsigned short* Kr    = (unsigned short*)p; p += (size_t)M * C * 2;
  unsigned short* Vt    = (unsigned short*)p; p += (size_t)M * C * 2;
  unsigned short* Ob    = xb;  // xb dead after QKV GEMM

  cast_kernel<<<M * C / 1024, 256, 0, stream>>>(x, xb, M * C);
  cast_kernel<<<N1 * C / 1024, 256, 0, stream>>>(Wqkv, wqkvb, N1 * C);
  cast_kernel<<<C * C / 1024, 256, 0, stream>>>(Wout, woutb, C * C);

  gemm256<0><<<dim3((M / 256) * (N1 / 256)), 512, 0, stream>>>(xb, wqkvb, bqkv, qkv, M, N1, C);

  rope_kernel<<<(32 * T * 64) / 256, 256, 0, stream>>>(qkv, Qr, Kr);
  vtrans_kernel<<<dim3(T / 64, 32), 256, 0, stream>>>(qkv, Vt);

  attn_fwd<<<dim3(32, T / 64), 256, 0, stream>>>(Qr, Kr, Vt, Ob, T);

  gemm256<1><<<dim3((M / 256) * (C / 256)), 512, 0, stream>>>(Ob, woutb, bout, out, M, C, C);
}

// Round 4
// 323.525 us; speedup vs baseline: 1.0445x; 1.0445x over previous
//
#include <hip/hip_runtime.h>
#include <hip/hip_bf16.h>

typedef __attribute__((ext_vector_type(8))) short bf16x8;
typedef __attribute__((ext_vector_type(4))) float f32x4;

#define GLOAD_LDS16(gptr, lptr) \
  __builtin_amdgcn_global_load_lds((const __attribute__((address_space(1))) void*)(gptr), \
                                   (__attribute__((address_space(3))) void*)(lptr), 16, 0, 0)

__device__ __forceinline__ unsigned short f2b(float f) {
  union { float f; unsigned u; } x; x.f = f;
  unsigned r = x.u + 0x7fffu + ((x.u >> 16) & 1u);
  return (unsigned short)(r >> 16);
}
__device__ __forceinline__ float b2f(unsigned short u) {
  union { unsigned u; float f; } x; x.u = ((unsigned)u) << 16;
  return x.f;
}

// ---------------- fp32 -> bf16 cast ----------------
__global__ void cast_kernel(const float* __restrict__ in, unsigned short* __restrict__ out, int n) {
  const int i = (blockIdx.x * 256 + threadIdx.x) * 4;
  if (i < n) {
    const float4 v = *(const float4*)(in + i);
    ushort4 r;
    r.x = f2b(v.x); r.y = f2b(v.y); r.z = f2b(v.z); r.w = f2b(v.w);
    *(ushort4*)(out + i) = r;
  }
}

// ---------------- GEMM 256x256, BK=64, 8-phase (m201 port) ----------------
// C[M][N] = A[M][K]*Bm[N][K]^T + bias. 8 waves (2M x 4N), per-wave 128x64.
// LDS 128KB: 2 slots x {A: h0,h1 | B: h0,h1} of 16KB halves.
// Per K-tile: 4 phases x {ds_read subtile, stage 1 half, barrier, lgkmcnt(0),
// setprio(1), 16 MFMA, setprio(0), barrier}; counted vmcnt(4) once per tile.
// Swizzle: a ^= ((a>>7)&7)<<4 (involution), pre-swizzled global source.
template<int OUTF32>
__global__ __launch_bounds__(512, 2)
void gemm256(const unsigned short* __restrict__ A,
             const unsigned short* __restrict__ Bm,
             const float* __restrict__ bias,
             void* __restrict__ Cp,
             int M, int N, int K)
{
  __shared__ __align__(16) char Lds[131072];
  const int t  = threadIdx.x;
  const int l  = t & 63;
  const int w  = t >> 6;
  const int lr = l & 15;
  const int lkb = (l >> 4) << 4;    // 0/16/32/48
  const int wr = w >> 2;            // A-half (M half)
  const int wc = w & 3;             // N quarter

  // XCD-aware block swizzle (grid % 8 == 0 for our shapes)
  const int nwg = gridDim.x;
  const int wg  = (blockIdx.x & 7) * (nwg >> 3) + (blockIdx.x >> 3);
  const int NBN = N >> 8;
  const int bm = wg / NBN, bn = wg % NBN;

  // read-side swizzled column constants: ckk = ((kk<<6)|lkb) ^ ((lr&7)<<4)
  const int sw3 = (lr & 7) << 4;
  const int ck0 = lkb ^ sw3;
  const int ck1 = (64 | lkb) ^ sw3;

  // staging: linear LDS dest lb; pre-swizzled source element d = swz(lb)
  const int lb0 = t << 4;
  const int lb1 = lb0 + 8192;
  const int d0 = lb0 ^ (((lb0 >> 7) & 7) << 4);
  const int d1 = lb1 ^ (((lb1 >> 7) & 7) << 4);
  const long K2 = (long)K * 2;
  const char* Ab = (const char*)A  + (long)(bm * 256) * K2;
  const char* Bb = (const char*)Bm + (long)(bn * 256) * K2;
  const long s0 = (long)(d0 >> 7) * K2 + (d0 & 127);
  const long s1 = (long)(d1 >> 7) * K2 + (d1 & 127);
  const long hstep = (long)128 * K2;

  auto stageA = [&](int g, int h) {
    char* dst = Lds + (g & 1) * 65536 + h * 16384;
    const char* src = Ab + (long)h * hstep + (long)g * 128;
    GLOAD_LDS16(src + s0, dst + lb0);
    GLOAD_LDS16(src + s1, dst + lb1);
  };
  auto stageB = [&](int g, int h) {
    char* dst = Lds + (g & 1) * 65536 + 32768 + h * 16384;
    const char* src = Bb + (long)h * hstep + (long)g * 128;
    GLOAD_LDS16(src + s0, dst + lb0);
    GLOAD_LDS16(src + s1, dst + lb1);
  };

  f32x4 acc[8][4] = {};
  const int NT = K >> 6;

  // prologue: A(0), B(0), B(1)  [A(1) comes from loop t=0 P1/P2]
  stageA(0, 0); stageA(0, 1);
  stageB(0, 0); stageB(0, 1);
  stageB(1, 0); stageB(1, 1);
  asm volatile("s_waitcnt vmcnt(4)" ::: "memory");   // tile0 complete
  __builtin_amdgcn_s_barrier();

  const int brow = ((wc & 1) * 64 + lr) << 7;   // B row-in-half base (bytes)

  for (int tt = 0; tt < NT; ++tt) {
    const char* SB = Lds + (tt & 1) * 65536;
    const char* AH = SB + wr * 16384;
    const char* BH = SB + 32768 + (wc >> 1) * 16384;
    bf16x8 af[4][2], blo[2][2], bhi[2][2];

    // ---- P1: af rows mi0-3, blo (ni0-1); stage A(t+1) h0 ----
#pragma unroll
    for (int mi = 0; mi < 4; ++mi) {
      af[mi][0] = *(const bf16x8*)(AH + ((mi * 16 + lr) << 7) + ck0);
      af[mi][1] = *(const bf16x8*)(AH + ((mi * 16 + lr) << 7) + ck1);
    }
#pragma unroll
    for (int ni = 0; ni < 2; ++ni) {
      blo[ni][0] = *(const bf16x8*)(BH + brow + (ni << 11) + ck0);
      blo[ni][1] = *(const bf16x8*)(BH + brow + (ni << 11) + ck1);
    }
    if (tt + 1 < NT) stageA(tt + 1, 0);
    __builtin_amdgcn_s_barrier();
    asm volatile("s_waitcnt lgkmcnt(0)" ::: "memory");
    __builtin_amdgcn_sched_barrier(0);
    __builtin_amdgcn_s_setprio(1);
#pragma unroll
    for (int mi = 0; mi < 4; ++mi)
#pragma unroll
      for (int ni = 0; ni < 2; ++ni) {
        acc[mi][ni] = __builtin_amdgcn_mfma_f32_16x16x32_bf16(af[mi][0], blo[ni][0], acc[mi][ni], 0, 0, 0);
        acc[mi][ni] = __builtin_amdgcn_mfma_f32_16x16x32_bf16(af[mi][1], blo[ni][1], acc[mi][ni], 0, 0, 0);
      }
    __builtin_amdgcn_s_setprio(0);
    __builtin_amdgcn_s_barrier();

    // ---- P2: bhi (ni2-3); stage A(t+1) h1 ----
#pragma unroll
    for (int ni = 0; ni < 2; ++ni) {
      bhi[ni][0] = *(const bf16x8*)(BH + brow + ((ni + 2) << 11) + ck0);
      bhi[ni][1] = *(const bf16x8*)(BH + brow + ((ni + 2) << 11) + ck1);
    }
    if (tt + 1 < NT) stageA(tt + 1, 1);
    __builtin_amdgcn_s_barrier();
    asm volatile("s_waitcnt lgkmcnt(0)" ::: "memory");
    __builtin_amdgcn_sched_barrier(0);
    __builtin_amdgcn_s_setprio(1);
#pragma unroll
    for (int mi = 0; mi < 4; ++mi)
#pragma unroll
      for (int ni = 0; ni < 2; ++ni) {
        acc[mi][ni + 2] = __builtin_amdgcn_mfma_f32_16x16x32_bf16(af[mi][0], bhi[ni][0], acc[mi][ni + 2], 0, 0, 0);
        acc[mi][ni + 2] = __builtin_amdgcn_mfma_f32_16x16x32_bf16(af[mi][1], bhi[ni][1], acc[mi][ni + 2], 0, 0, 0);
      }
    __builtin_amdgcn_s_setprio(0);
    __builtin_amdgcn_s_barrier();

    // ---- P3: af rows mi4-7; stage B(t+2) h0 (B halves of slot dead after P2) ----
#pragma unroll
    for (int mi = 0; mi < 4; ++mi) {
      af[mi][0] = *(const bf16x8*)(AH + ((64 + mi * 16 + lr) << 7) + ck0);
      af[mi][1] = *(const bf16x8*)(AH + ((64 + mi * 16 + lr) << 7) + ck1);
    }
    if (tt + 2 < NT) stageB(tt + 2, 0);
    __builtin_amdgcn_s_barrier();
    asm volatile("s_waitcnt lgkmcnt(0)" ::: "memory");
    __builtin_amdgcn_sched_barrier(0);
    __builtin_amdgcn_s_setprio(1);
#pragma unroll
    for (int mi = 0; mi < 4; ++mi)
#pragma unroll
      for (int ni = 0; ni < 2; ++ni) {
        acc[mi + 4][ni] = __builtin_amdgcn_mfma_f32_16x16x32_bf16(af[mi][0], blo[ni][0], acc[mi + 4][ni], 0, 0, 0);
        acc[mi + 4][ni] = __builtin_amdgcn_mfma_f32_16x16x32_bf16(af[mi][1], blo[ni][1], acc[mi + 4][ni], 0, 0, 0);
      }
    __builtin_amdgcn_s_setprio(0);
    __builtin_amdgcn_s_barrier();

    // ---- P4: no reads; stage B(t+2) h1; counted vmcnt; single barrier ----
    if (tt + 2 < NT) stageB(tt + 2, 1);
    __builtin_amdgcn_s_setprio(1);
#pragma unroll
    for (int mi = 0; mi < 4; ++mi)
#pragma unroll
      for (int ni = 0; ni < 2; ++ni) {
        acc[mi + 4][ni + 2] = __builtin_amdgcn_mfma_f32_16x16x32_bf16(af[mi][0], bhi[ni][0], acc[mi + 4][ni + 2], 0, 0, 0);
        acc[mi + 4][ni + 2] = __builtin_amdgcn_mfma_f32_16x16x32_bf16(af[mi][1], bhi[ni][1], acc[mi + 4][ni + 2], 0, 0, 0);
      }
    __builtin_amdgcn_s_setprio(0);
    // drain A(t+1) [oldest 4 of the 8 outstanding]; keep B(t+2) in flight
    asm volatile("s_waitcnt vmcnt(4)" ::: "memory");
    __builtin_amdgcn_s_barrier();
  }

  // epilogue (C/D layout: col=lane&15, row=(lane>>4)*4+reg)
  const int roff = (l >> 4) << 2;
  const int row0 = bm * 256 + wr * 128 + roff;
  const int col0 = bn * 256 + wc * 64 + lr;
#pragma unroll
  for (int ni = 0; ni < 4; ++ni) {
    const int col = col0 + ni * 16;
    const float bv = bias ? bias[col] : 0.0f;
#pragma unroll
    for (int mi = 0; mi < 8; ++mi) {
#pragma unroll
      for (int r = 0; r < 4; ++r) {
        const int row = row0 + mi * 16 + r;
        const float v = acc[mi][ni][r] + bv;
        if (OUTF32) ((float*)Cp)[(long)row * N + col] = v;
        else ((unsigned short*)Cp)[(long)row * N + col] = f2b(v);
      }
    }
  }
}

// ---------------- RoPE: qkv[B][T][3][H*128] -> Qr,Kr (B,H,T,D) bf16 ----------------
__global__ void rope_kernel(const unsigned short* __restrict__ qkv,
                            unsigned short* __restrict__ Qr,
                            unsigned short* __restrict__ Kr)
{
  const int T = 2048;
  const int idx = blockIdx.x * 256 + threadIdx.x;
  const int d  = idx & 63;
  const int tt = (idx >> 6) & (T - 1);
  const int bh = idx >> 17;
  const int b = bh >> 4, h = bh & 15;
  const long base = ((long)(b * T + tt) * 3) * 2048 + h * 128;
  const float inv = exp2f(-(float)d * 0.2076205059304602f);
  const float fr = (float)tt * inv;
  float sn, cs;
  sincosf(fr, &sn, &cs);
  const float q1 = b2f(qkv[base + 2 * d]);
  const float q2 = b2f(qkv[base + 2 * d + 1]);
  const float k1 = b2f(qkv[base + 2048 + 2 * d]);
  const float k2 = b2f(qkv[base + 2048 + 2 * d + 1]);
  const long ob = ((long)bh * T + tt) * 128;
  Qr[ob + d]      = f2b(q1 * cs - q2 * sn);
  Qr[ob + 64 + d] = f2b(q1 * sn + q2 * cs);
  Kr[ob + d]      = f2b(k1 * cs - k2 * sn);
  Kr[ob + 64 + d] = f2b(k1 * sn + k2 * cs);
}

// ---------------- V transpose: qkv(...,s=2,...) -> Vt (B,H,D,T) bf16 ----------------
__global__ void vtrans_kernel(const unsigned short* __restrict__ qkv,
                              unsigned short* __restrict__ Vt)
{
  const int T = 2048;
  __shared__ unsigned short ld[128][65];
  const int bh = blockIdx.y, tt = blockIdx.x;
  const int b = bh >> 4, h = bh & 15;
  const int t = threadIdx.x;
#pragma unroll
  for (int i = 0; i < 32; ++i) {
    const int idx = i * 256 + t;
    const int d = idx & 127, tr = idx >> 7;
    ld[d][tr] = qkv[((long)(b * T + tt * 64 + tr) * 3 + 2) * 2048 + h * 128 + d];
  }
  __syncthreads();
#pragma unroll
  for (int i = 0; i < 32; ++i) {
    const int idx = i * 256 + t;
    const int tc = idx & 63, dr = idx >> 6;
    Vt[((long)bh * 128 + dr) * T + tt * 64 + tc] = ld[dr][tc];
  }
}

// ---------------- causal flash attention ----------------
__global__ __launch_bounds__(256)
void attn_fwd(const unsigned short* __restrict__ Q,
              const unsigned short* __restrict__ Kg,
              const unsigned short* __restrict__ Vt,
              unsigned short* __restrict__ O, int T)
{
  __shared__ __align__(16) unsigned short Ks[2][64 * 128];
  __shared__ __align__(16) unsigned short Vs[2][128 * 64];
  __shared__ __align__(16) unsigned short Ps[4][16 * 64];
  const int t = threadIdx.x;
  const int w = t >> 6, l = t & 63;
  const int lr = l & 15;
  const int g16 = (l >> 4) << 4;
  const int sw = (lr & 7) << 4;
  const int bh = blockIdx.x;
  const int qt = (gridDim.y - 1) - blockIdx.y;
  const int q0 = qt * 64 + w * 16;
  const long hbase = (long)bh * T * 128;
  const long hbase2 = hbase * 2;
  const long T2 = (long)T * 2;
  const int roff = (l >> 4) << 2;

  bf16x8 qf[4];
  const unsigned short* Qrow = Q + hbase + (long)(q0 + lr) * 128;
#pragma unroll
  for (int ds = 0; ds < 4; ++ds) qf[ds] = *(const bf16x8*)&Qrow[ds * 32 + (g16 >> 1)];

  f32x4 o[8] = {};
  float m[4]    = {-INFINITY, -INFINITY, -INFINITY, -INFINITY};
  float lsum[4] = {0.f, 0.f, 0.f, 0.f};

  auto stage = [&](int kt, int buf) {
#pragma unroll
    for (int c = 0; c < 4; ++c) {
      const int o2 = t * 16 + c * 4096;
      const int krow = o2 >> 8, kcb = o2 & 255;
      GLOAD_LDS16((const char*)Kg + hbase2 + (long)kt * 16384 + krow * 256 + (kcb ^ ((krow & 7) << 4)),
                  (char*)Ks[buf] + o2);
      const int vrow = o2 >> 7, vcb = o2 & 127;
      GLOAD_LDS16((const char*)Vt + (long)(bh * 128 + vrow) * T2 + (long)kt * 128 + (vcb ^ ((vrow & 7) << 4)),
                  (char*)Vs[buf] + o2);
    }
  };

  const int ntile = qt + 1;
  stage(0, 0);
  __syncthreads();

  for (int kt = 0; kt < ntile; ++kt) {
    const int cur = kt & 1;
    if (kt + 1 < ntile) stage(kt + 1, cur ^ 1);

    const char* KsB = (const char*)Ks[cur];
    const char* VsB = (const char*)Vs[cur];

    f32x4 s[4] = {};
    __builtin_amdgcn_s_setprio(1);
#pragma unroll
    for (int tj = 0; tj < 4; ++tj)
#pragma unroll
      for (int ds = 0; ds < 4; ++ds) {
        bf16x8 kf = *(const bf16x8*)(KsB + (tj * 16 + lr) * 256 + ((ds * 64 + g16) ^ sw));
        s[tj] = __builtin_amdgcn_mfma_f32_16x16x32_bf16(qf[ds], kf, s[tj], 0, 0, 0);
      }
    __builtin_amdgcn_s_setprio(0);

    const float scale = 0.08838834764831845f;
#pragma unroll
    for (int tj = 0; tj < 4; ++tj) s[tj] *= scale;
    if (kt == qt) {
#pragma unroll
      for (int tj = 0; tj < 4; ++tj)
#pragma unroll
        for (int j = 0; j < 4; ++j)
          if (kt * 64 + tj * 16 + lr > q0 + roff + j) s[tj][j] = -INFINITY;
    }

    float corr[4];
#pragma unroll
    for (int j = 0; j < 4; ++j) {
      float v = fmaxf(fmaxf(s[0][j], s[1][j]), fmaxf(s[2][j], s[3][j]));
      v = fmaxf(v, __shfl_xor(v, 1, 64));
      v = fmaxf(v, __shfl_xor(v, 2, 64));
      v = fmaxf(v, __shfl_xor(v, 4, 64));
      v = fmaxf(v, __shfl_xor(v, 8, 64));
      const float mn = fmaxf(m[j], v);
      corr[j] = __expf(m[j] - mn);
      m[j] = mn;
    }
    float rs[4] = {0.f, 0.f, 0.f, 0.f};
#pragma unroll
    for (int tj = 0; tj < 4; ++tj)
#pragma unroll
      for (int j = 0; j < 4; ++j) {
        const float p = __expf(s[tj][j] - m[j]);
        rs[j] += p;
        const int prow = roff + j;
        *(unsigned short*)((char*)Ps[w] + prow * 128 + (((tj * 16 + lr) * 2) ^ ((prow & 7) << 4))) = f2b(p);
      }
#pragma unroll
    for (int j = 0; j < 4; ++j) {
      float v = rs[j];
      v += __shfl_xor(v, 1, 64);
      v += __shfl_xor(v, 2, 64);
      v += __shfl_xor(v, 4, 64);
      v += __shfl_xor(v, 8, 64);
      lsum[j] = lsum[j] * corr[j] + v;
    }
#pragma unroll
    for (int nj = 0; nj < 8; ++nj)
#pragma unroll
      for (int j = 0; j < 4; ++j) o[nj][j] *= corr[j];

    __builtin_amdgcn_s_setprio(1);
#pragma unroll
    for (int ks = 0; ks < 2; ++ks) {
      bf16x8 pf = *(const bf16x8*)((const char*)Ps[w] + lr * 128 + ((ks * 64 + g16) ^ sw));
#pragma unroll
      for (int nj = 0; nj < 8; ++nj) {
        bf16x8 vf = *(const bf16x8*)(VsB + (nj * 16 + lr) * 128 + ((ks * 64 + g16) ^ sw));
        o[nj] = __builtin_amdgcn_mfma_f32_16x16x32_bf16(pf, vf, o[nj], 0, 0, 0);
      }
    }
    __builtin_amdgcn_s_setprio(0);
    __syncthreads();
  }

  float inv[4];
#pragma unroll
  for (int j = 0; j < 4; ++j) inv[j] = 1.0f / lsum[j];
  const int b = bh >> 4, h = bh & 15;
#pragma unroll
  for (int nj = 0; nj < 8; ++nj)
#pragma unroll
    for (int j = 0; j < 4; ++j) {
      const int q = q0 + roff + j;
      const int d = nj * 16 + lr;
      O[(long)(b * T + q) * 2048 + h * 128 + d] = f2b(o[nj][j] * inv[j]);
    }
}

// ---------------- launch ----------------
extern "C" void kernel_launch(void* const* d_in, const int* in_sizes, int n_in,
                              void* d_out, int out_size, void* d_ws, size_t ws_size,
                              hipStream_t stream)
{
  const int B = 2, T = 2048, C = 2048;
  const int M = B * T;        // 4096
  const int N1 = 3 * C;       // 6144
  const float* x    = (const float*)d_in[0];
  const float* Wqkv = (const float*)d_in[1];
  const float* bqkv = (const float*)d_in[2];
  const float* Wout = (const float*)d_in[3];
  const float* bout = (const float*)d_in[4];
  float* out = (float*)d_out;

  char* p = (char*)d_ws;
  unsigned short* xb    = (unsigned short*)p; p += (size_t)M * C * 2;
  unsigned short* wqkvb = (unsigned short*)p; p += (size_t)N1 * C * 2;
  unsigned short* woutb = (unsigned short*)p; p += (size_t)C * C * 2;
  unsigned short* qkv   = (unsigned short*)p; p += (size_t)M * N1 * 2;
  unsigned short* Qr    = (unsigned short*)p; p += (size_t)M * C * 2;
  unsigned short* Kr    = (unsigned short*)p; p += (size_t)M * C * 2;
  unsigned short* Vt    = (unsigned short*)p; p += (size_t)M * C * 2;
  unsigned short* Ob    = xb;  // xb dead after QKV GEMM

  cast_kernel<<<M * C / 1024, 256, 0, stream>>>(x, xb, M * C);
  cast_kernel<<<N1 * C / 1024, 256, 0, stream>>>(Wqkv, wqkvb, N1 * C);
  cast_kernel<<<C * C / 1024, 256, 0, stream>>>(Wout, woutb, C * C);

  gemm256<0><<<dim3((M / 256) * (N1 / 256)), 512, 0, stream>>>(xb, wqkvb, bqkv, qkv, M, N1, C);

  rope_kernel<<<(32 * T * 64) / 256, 256, 0, stream>>>(qkv, Qr, Kr);
  vtrans_kernel<<<dim3(T / 64, 32), 256, 0, stream>>>(qkv, Vt);

  attn_fwd<<<dim3(32, T / 64), 256, 0, stream>>>(Qr, Kr, Vt, Ob, T);

  gemm256<1><<<dim3((M / 256) * (C / 256)), 512, 0, stream>>>(Ob, woutb, bout, out, M, C, C);
}

// Round 5
// 320.972 us; speedup vs baseline: 1.0528x; 1.0080x over previous
//
#include <hip/hip_runtime.h>
#include <hip/hip_bf16.h>

typedef __attribute__((ext_vector_type(8))) short bf16x8;
typedef __attribute__((ext_vector_type(4))) float f32x4;

#define GLOAD_LDS16(gptr, lptr) \
  __builtin_amdgcn_global_load_lds((const __attribute__((address_space(1))) void*)(gptr), \
                                   (__attribute__((address_space(3))) void*)(lptr), 16, 0, 0)

__device__ __forceinline__ unsigned short f2b(float f) {
  union { float f; unsigned u; } x; x.f = f;
  unsigned r = x.u + 0x7fffu + ((x.u >> 16) & 1u);
  return (unsigned short)(r >> 16);
}
__device__ __forceinline__ float b2f(unsigned short u) {
  union { unsigned u; float f; } x; x.u = ((unsigned)u) << 16;
  return x.f;
}

// ---------------- fp32 -> bf16 cast ----------------
__global__ void cast_kernel(const float* __restrict__ in, unsigned short* __restrict__ out, int n) {
  const int i = (blockIdx.x * 256 + threadIdx.x) * 4;
  if (i < n) {
    const float4 v = *(const float4*)(in + i);
    ushort4 r;
    r.x = f2b(v.x); r.y = f2b(v.y); r.z = f2b(v.z); r.w = f2b(v.w);
    *(ushort4*)(out + i) = r;
  }
}

// ---------------- GEMM 256x256, BK=64, read-ahead pipelined ----------------
// C[M][N] = A[M][K]*Bm[N][K]^T + bias. 8 waves (2M x 4N), per-wave 128x64.
// LDS 128KB: 2 slots x {A h0,h1 | B h0,h1} of 16KB. Same layout/staging as R4.
// ds_reads issued at register-death points (one+ phase before use) so the
// compiler's counted lgkm waits keep LDS drain under MFMA (T3/T4 in lgkm domain).
// One vmcnt(0) per tile at P3 (newest drained load has >=2 phases of flight).
template<int OUTF32>
__global__ __launch_bounds__(512, 2)
void gemm256(const unsigned short* __restrict__ A,
             const unsigned short* __restrict__ Bm,
             const float* __restrict__ bias,
             void* __restrict__ Cp,
             int M, int N, int K)
{
  __shared__ __align__(16) char Lds[131072];
  const int t  = threadIdx.x;
  const int l  = t & 63;
  const int w  = t >> 6;
  const int lr = l & 15;
  const int lkb = (l >> 4) << 4;    // 0/16/32/48
  const int wr = w >> 2;            // A-half (M half)
  const int wc = w & 3;             // N quarter

  // XCD-aware block swizzle (grid % 8 == 0 for our shapes)
  const int nwg = gridDim.x;
  const int wg  = (blockIdx.x & 7) * (nwg >> 3) + (blockIdx.x >> 3);
  const int NBN = N >> 8;
  const int bm = wg / NBN, bn = wg % NBN;

  // read-side swizzled column constants
  const int sw3 = (lr & 7) << 4;
  const int ck0 = lkb ^ sw3;
  const int ck1 = (64 | lkb) ^ sw3;

  // staging: linear LDS dest lb; pre-swizzled source element d = swz(lb)
  const int lb0 = t << 4;
  const int lb1 = lb0 + 8192;
  const int d0 = lb0 ^ (((lb0 >> 7) & 7) << 4);
  const int d1 = lb1 ^ (((lb1 >> 7) & 7) << 4);
  const long K2 = (long)K * 2;
  const char* Ab = (const char*)A  + (long)(bm * 256) * K2;
  const char* Bb = (const char*)Bm + (long)(bn * 256) * K2;
  const long s0 = (long)(d0 >> 7) * K2 + (d0 & 127);
  const long s1 = (long)(d1 >> 7) * K2 + (d1 & 127);
  const long hstep = (long)128 * K2;

  auto stageA = [&](int g, int h) {
    char* dst = Lds + (g & 1) * 65536 + h * 16384;
    const char* src = Ab + (long)h * hstep + (long)g * 128;
    GLOAD_LDS16(src + s0, dst + lb0);
    GLOAD_LDS16(src + s1, dst + lb1);
  };
  auto stageB = [&](int g, int h) {
    char* dst = Lds + (g & 1) * 65536 + 32768 + h * 16384;
    const char* src = Bb + (long)h * hstep + (long)g * 128;
    GLOAD_LDS16(src + s0, dst + lb0);
    GLOAD_LDS16(src + s1, dst + lb1);
  };

  f32x4 acc[8][4] = {};
  const int NT = K >> 6;
  const int brow = ((wc & 1) * 64 + lr) << 7;   // B row base within half (bytes)

  bf16x8 af[4][2], blo[2][2], bhi[2][2];

  // ---- prologue: stage A(0), B(0), B(1); bootstrap reads for tile 0 ----
  stageA(0, 0); stageA(0, 1);
  stageB(0, 0); stageB(0, 1);
  stageB(1, 0); stageB(1, 1);
  asm volatile("s_waitcnt vmcnt(4)" ::: "memory");   // A(0), B(0) landed
  __builtin_amdgcn_s_barrier();
  {
    const char* AH0 = Lds + wr * 16384;
    const char* BH0 = Lds + 32768 + (wc >> 1) * 16384;
#pragma unroll
    for (int ni = 0; ni < 2; ++ni) {
      blo[ni][0] = *(const bf16x8*)(BH0 + brow + (ni << 11) + ck0);
      blo[ni][1] = *(const bf16x8*)(BH0 + brow + (ni << 11) + ck1);
    }
#pragma unroll
    for (int mi = 0; mi < 4; ++mi) {
      af[mi][0] = *(const bf16x8*)(AH0 + ((mi * 16 + lr) << 7) + ck0);
      af[mi][1] = *(const bf16x8*)(AH0 + ((mi * 16 + lr) << 7) + ck1);
    }
#pragma unroll
    for (int ni = 0; ni < 2; ++ni) {
      bhi[ni][0] = *(const bf16x8*)(BH0 + brow + ((ni + 2) << 11) + ck0);
      bhi[ni][1] = *(const bf16x8*)(BH0 + brow + ((ni + 2) << 11) + ck1);
    }
  }

  for (int tt = 0; tt < NT; ++tt) {
    const char* SB = Lds + (tt & 1) * 65536;
    const char* AH = SB + wr * 16384;

    // ---- P1: stage A(t+1); MFMA lo x blo (af_lo/blo read last tile) ----
    if (tt + 1 < NT) { stageA(tt + 1, 0); stageA(tt + 1, 1); }
    __builtin_amdgcn_s_barrier();
    __builtin_amdgcn_sched_barrier(0);
    __builtin_amdgcn_s_setprio(1);
#pragma unroll
    for (int mi = 0; mi < 4; ++mi)
#pragma unroll
      for (int ni = 0; ni < 2; ++ni) {
        acc[mi][ni] = __builtin_amdgcn_mfma_f32_16x16x32_bf16(af[mi][0], blo[ni][0], acc[mi][ni], 0, 0, 0);
        acc[mi][ni] = __builtin_amdgcn_mfma_f32_16x16x32_bf16(af[mi][1], blo[ni][1], acc[mi][ni], 0, 0, 0);
      }
    __builtin_amdgcn_s_setprio(0);
    __builtin_amdgcn_s_barrier();
    __builtin_amdgcn_sched_barrier(0);

    // ---- P2: MFMA lo x bhi; then read af_hi(t) into af (lo regs dead) ----
    __builtin_amdgcn_s_setprio(1);
#pragma unroll
    for (int mi = 0; mi < 4; ++mi)
#pragma unroll
      for (int ni = 0; ni < 2; ++ni) {
        acc[mi][ni + 2] = __builtin_amdgcn_mfma_f32_16x16x32_bf16(af[mi][0], bhi[ni][0], acc[mi][ni + 2], 0, 0, 0);
        acc[mi][ni + 2] = __builtin_amdgcn_mfma_f32_16x16x32_bf16(af[mi][1], bhi[ni][1], acc[mi][ni + 2], 0, 0, 0);
      }
    __builtin_amdgcn_s_setprio(0);
#pragma unroll
    for (int mi = 0; mi < 4; ++mi) {
      af[mi][0] = *(const bf16x8*)(AH + ((64 + mi * 16 + lr) << 7) + ck0);
      af[mi][1] = *(const bf16x8*)(AH + ((64 + mi * 16 + lr) << 7) + ck1);
    }
    __builtin_amdgcn_s_barrier();
    __builtin_amdgcn_sched_barrier(0);

    // ---- P3: drain vmem; stage B(t+2)h0; MFMA hi x blo; read blo(t+1) ----
    asm volatile("s_waitcnt vmcnt(0)" ::: "memory");  // A(t+1), B(t+1) landed
    if (tt + 2 < NT) stageB(tt + 2, 0);
    __builtin_amdgcn_s_setprio(1);
#pragma unroll
    for (int mi = 0; mi < 4; ++mi)
#pragma unroll
      for (int ni = 0; ni < 2; ++ni) {
        acc[mi + 4][ni] = __builtin_amdgcn_mfma_f32_16x16x32_bf16(af[mi][0], blo[ni][0], acc[mi + 4][ni], 0, 0, 0);
        acc[mi + 4][ni] = __builtin_amdgcn_mfma_f32_16x16x32_bf16(af[mi][1], blo[ni][1], acc[mi + 4][ni], 0, 0, 0);
      }
    __builtin_amdgcn_s_setprio(0);
    if (tt + 1 < NT) {
      const char* BHn = Lds + ((tt + 1) & 1) * 65536 + 32768 + (wc >> 1) * 16384;
#pragma unroll
      for (int ni = 0; ni < 2; ++ni) {
        blo[ni][0] = *(const bf16x8*)(BHn + brow + (ni << 11) + ck0);
        blo[ni][1] = *(const bf16x8*)(BHn + brow + (ni << 11) + ck1);
      }
    }
    __builtin_amdgcn_s_barrier();
    __builtin_amdgcn_sched_barrier(0);

    // ---- P4: stage B(t+2)h1; MFMA hi x bhi; read af_lo(t+1), bhi(t+1) ----
    if (tt + 2 < NT) stageB(tt + 2, 1);
    __builtin_amdgcn_s_setprio(1);
#pragma unroll
    for (int mi = 0; mi < 4; ++mi)
#pragma unroll
      for (int ni = 0; ni < 2; ++ni) {
        acc[mi + 4][ni + 2] = __builtin_amdgcn_mfma_f32_16x16x32_bf16(af[mi][0], bhi[ni][0], acc[mi + 4][ni + 2], 0, 0, 0);
        acc[mi + 4][ni + 2] = __builtin_amdgcn_mfma_f32_16x16x32_bf16(af[mi][1], bhi[ni][1], acc[mi + 4][ni + 2], 0, 0, 0);
      }
    __builtin_amdgcn_s_setprio(0);
    if (tt + 1 < NT) {
      const char* SBn = Lds + ((tt + 1) & 1) * 65536;
      const char* AHn = SBn + wr * 16384;
      const char* BHn = SBn + 32768 + (wc >> 1) * 16384;
#pragma unroll
      for (int mi = 0; mi < 4; ++mi) {
        af[mi][0] = *(const bf16x8*)(AHn + ((mi * 16 + lr) << 7) + ck0);
        af[mi][1] = *(const bf16x8*)(AHn + ((mi * 16 + lr) << 7) + ck1);
      }
#pragma unroll
      for (int ni = 0; ni < 2; ++ni) {
        bhi[ni][0] = *(const bf16x8*)(BHn + brow + ((ni + 2) << 11) + ck0);
        bhi[ni][1] = *(const bf16x8*)(BHn + brow + ((ni + 2) << 11) + ck1);
      }
    }
    __builtin_amdgcn_s_barrier();
    __builtin_amdgcn_sched_barrier(0);
  }

  // epilogue (C/D layout: col=lane&15, row=(lane>>4)*4+reg)
  const int roff = (l >> 4) << 2;
  const int row0 = bm * 256 + wr * 128 + roff;
  const int col0 = bn * 256 + wc * 64 + lr;
#pragma unroll
  for (int ni = 0; ni < 4; ++ni) {
    const int col = col0 + ni * 16;
    const float bv = bias ? bias[col] : 0.0f;
#pragma unroll
    for (int mi = 0; mi < 8; ++mi) {
#pragma unroll
      for (int r = 0; r < 4; ++r) {
        const int row = row0 + mi * 16 + r;
        const float v = acc[mi][ni][r] + bv;
        if (OUTF32) ((float*)Cp)[(long)row * N + col] = v;
        else ((unsigned short*)Cp)[(long)row * N + col] = f2b(v);
      }
    }
  }
}

// ---------------- RoPE: qkv[B][T][3][H*128] -> Qr,Kr (B,H,T,D) bf16 ----------------
__global__ void rope_kernel(const unsigned short* __restrict__ qkv,
                            unsigned short* __restrict__ Qr,
                            unsigned short* __restrict__ Kr)
{
  const int T = 2048;
  const int idx = blockIdx.x * 256 + threadIdx.x;
  const int d  = idx & 63;
  const int tt = (idx >> 6) & (T - 1);
  const int bh = idx >> 17;
  const int b = bh >> 4, h = bh & 15;
  const long base = ((long)(b * T + tt) * 3) * 2048 + h * 128;
  const float inv = exp2f(-(float)d * 0.2076205059304602f);
  const float fr = (float)tt * inv;
  float sn, cs;
  sincosf(fr, &sn, &cs);
  const float q1 = b2f(qkv[base + 2 * d]);
  const float q2 = b2f(qkv[base + 2 * d + 1]);
  const float k1 = b2f(qkv[base + 2048 + 2 * d]);
  const float k2 = b2f(qkv[base + 2048 + 2 * d + 1]);
  const long ob = ((long)bh * T + tt) * 128;
  Qr[ob + d]      = f2b(q1 * cs - q2 * sn);
  Qr[ob + 64 + d] = f2b(q1 * sn + q2 * cs);
  Kr[ob + d]      = f2b(k1 * cs - k2 * sn);
  Kr[ob + 64 + d] = f2b(k1 * sn + k2 * cs);
}

// ---------------- V transpose: qkv(...,s=2,...) -> Vt (B,H,D,T) bf16 ----------------
__global__ void vtrans_kernel(const unsigned short* __restrict__ qkv,
                              unsigned short* __restrict__ Vt)
{
  const int T = 2048;
  __shared__ unsigned short ld[128][65];
  const int bh = blockIdx.y, tt = blockIdx.x;
  const int b = bh >> 4, h = bh & 15;
  const int t = threadIdx.x;
#pragma unroll
  for (int i = 0; i < 32; ++i) {
    const int idx = i * 256 + t;
    const int d = idx & 127, tr = idx >> 7;
    ld[d][tr] = qkv[((long)(b * T + tt * 64 + tr) * 3 + 2) * 2048 + h * 128 + d];
  }
  __syncthreads();
#pragma unroll
  for (int i = 0; i < 32; ++i) {
    const int idx = i * 256 + t;
    const int tc = idx & 63, dr = idx >> 6;
    Vt[((long)bh * 128 + dr) * T + tt * 64 + tc] = ld[dr][tc];
  }
}

// ---------------- causal flash attention ----------------
__global__ __launch_bounds__(256)
void attn_fwd(const unsigned short* __restrict__ Q,
              const unsigned short* __restrict__ Kg,
              const unsigned short* __restrict__ Vt,
              unsigned short* __restrict__ O, int T)
{
  __shared__ __align__(16) unsigned short Ks[2][64 * 128];
  __shared__ __align__(16) unsigned short Vs[2][128 * 64];
  __shared__ __align__(16) unsigned short Ps[4][16 * 64];
  const int t = threadIdx.x;
  const int w = t >> 6, l = t & 63;
  const int lr = l & 15;
  const int g16 = (l >> 4) << 4;
  const int sw = (lr & 7) << 4;
  const int bh = blockIdx.x;
  const int qt = (gridDim.y - 1) - blockIdx.y;
  const int q0 = qt * 64 + w * 16;
  const long hbase = (long)bh * T * 128;
  const long hbase2 = hbase * 2;
  const long T2 = (long)T * 2;
  const int roff = (l >> 4) << 2;

  bf16x8 qf[4];
  const unsigned short* Qrow = Q + hbase + (long)(q0 + lr) * 128;
#pragma unroll
  for (int ds = 0; ds < 4; ++ds) qf[ds] = *(const bf16x8*)&Qrow[ds * 32 + (g16 >> 1)];

  f32x4 o[8] = {};
  float m[4]    = {-INFINITY, -INFINITY, -INFINITY, -INFINITY};
  float lsum[4] = {0.f, 0.f, 0.f, 0.f};

  auto stage = [&](int kt, int buf) {
#pragma unroll
    for (int c = 0; c < 4; ++c) {
      const int o2 = t * 16 + c * 4096;
      const int krow = o2 >> 8, kcb = o2 & 255;
      GLOAD_LDS16((const char*)Kg + hbase2 + (long)kt * 16384 + krow * 256 + (kcb ^ ((krow & 7) << 4)),
                  (char*)Ks[buf] + o2);
      const int vrow = o2 >> 7, vcb = o2 & 127;
      GLOAD_LDS16((const char*)Vt + (long)(bh * 128 + vrow) * T2 + (long)kt * 128 + (vcb ^ ((vrow & 7) << 4)),
                  (char*)Vs[buf] + o2);
    }
  };

  const int ntile = qt + 1;
  stage(0, 0);
  __syncthreads();

  for (int kt = 0; kt < ntile; ++kt) {
    const int cur = kt & 1;
    if (kt + 1 < ntile) stage(kt + 1, cur ^ 1);

    const char* KsB = (const char*)Ks[cur];
    const char* VsB = (const char*)Vs[cur];

    f32x4 s[4] = {};
    __builtin_amdgcn_s_setprio(1);
#pragma unroll
    for (int tj = 0; tj < 4; ++tj)
#pragma unroll
      for (int ds = 0; ds < 4; ++ds) {
        bf16x8 kf = *(const bf16x8*)(KsB + (tj * 16 + lr) * 256 + ((ds * 64 + g16) ^ sw));
        s[tj] = __builtin_amdgcn_mfma_f32_16x16x32_bf16(qf[ds], kf, s[tj], 0, 0, 0);
      }
    __builtin_amdgcn_s_setprio(0);

    const float scale = 0.08838834764831845f;
#pragma unroll
    for (int tj = 0; tj < 4; ++tj) s[tj] *= scale;
    if (kt == qt) {
#pragma unroll
      for (int tj = 0; tj < 4; ++tj)
#pragma unroll
        for (int j = 0; j < 4; ++j)
          if (kt * 64 + tj * 16 + lr > q0 + roff + j) s[tj][j] = -INFINITY;
    }

    float corr[4];
#pragma unroll
    for (int j = 0; j < 4; ++j) {
      float v = fmaxf(fmaxf(s[0][j], s[1][j]), fmaxf(s[2][j], s[3][j]));
      v = fmaxf(v, __shfl_xor(v, 1, 64));
      v = fmaxf(v, __shfl_xor(v, 2, 64));
      v = fmaxf(v, __shfl_xor(v, 4, 64));
      v = fmaxf(v, __shfl_xor(v, 8, 64));
      const float mn = fmaxf(m[j], v);
      corr[j] = __expf(m[j] - mn);
      m[j] = mn;
    }
    float rs[4] = {0.f, 0.f, 0.f, 0.f};
#pragma unroll
    for (int tj = 0; tj < 4; ++tj)
#pragma unroll
      for (int j = 0; j < 4; ++j) {
        const float p = __expf(s[tj][j] - m[j]);
        rs[j] += p;
        const int prow = roff + j;
        *(unsigned short*)((char*)Ps[w] + prow * 128 + (((tj * 16 + lr) * 2) ^ ((prow & 7) << 4))) = f2b(p);
      }
#pragma unroll
    for (int j = 0; j < 4; ++j) {
      float v = rs[j];
      v += __shfl_xor(v, 1, 64);
      v += __shfl_xor(v, 2, 64);
      v += __shfl_xor(v, 4, 64);
      v += __shfl_xor(v, 8, 64);
      lsum[j] = lsum[j] * corr[j] + v;
    }
#pragma unroll
    for (int nj = 0; nj < 8; ++nj)
#pragma unroll
      for (int j = 0; j < 4; ++j) o[nj][j] *= corr[j];

    __builtin_amdgcn_s_setprio(1);
#pragma unroll
    for (int ks = 0; ks < 2; ++ks) {
      bf16x8 pf = *(const bf16x8*)((const char*)Ps[w] + lr * 128 + ((ks * 64 + g16) ^ sw));
#pragma unroll
      for (int nj = 0; nj < 8; ++nj) {
        bf16x8 vf = *(const bf16x8*)(VsB + (nj * 16 + lr) * 128 + ((ks * 64 + g16) ^ sw));
        o[nj] = __builtin_amdgcn_mfma_f32_16x16x32_bf16(pf, vf, o[nj], 0, 0, 0);
      }
    }
    __builtin_amdgcn_s_setprio(0);
    __syncthreads();
  }

  float inv[4];
#pragma unroll
  for (int j = 0; j < 4; ++j) inv[j] = 1.0f / lsum[j];
  const int b = bh >> 4, h = bh & 15;
#pragma unroll
  for (int nj = 0; nj < 8; ++nj)
#pragma unroll
    for (int j = 0; j < 4; ++j) {
      const int q = q0 + roff + j;
      const int d = nj * 16 + lr;
      O[(long)(b * T + q) * 2048 + h * 128 + d] = f2b(o[nj][j] * inv[j]);
    }
}

// ---------------- launch ----------------
extern "C" void kernel_launch(void* const* d_in, const int* in_sizes, int n_in,
                              void* d_out, int out_size, void* d_ws, size_t ws_size,
                              hipStream_t stream)
{
  const int B = 2, T = 2048, C = 2048;
  const int M = B * T;        // 4096
  const int N1 = 3 * C;       // 6144
  const float* x    = (const float*)d_in[0];
  const float* Wqkv = (const float*)d_in[1];
  const float* bqkv = (const float*)d_in[2];
  const float* Wout = (const float*)d_in[3];
  const float* bout = (const float*)d_in[4];
  float* out = (float*)d_out;

  char* p = (char*)d_ws;
  unsigned short* xb    = (unsigned short*)p; p += (size_t)M * C * 2;
  unsigned short* wqkvb = (unsigned short*)p; p += (size_t)N1 * C * 2;
  unsigned short* woutb = (unsigned short*)p; p += (size_t)C * C * 2;
  unsigned short* qkv   = (unsigned short*)p; p += (size_t)M * N1 * 2;
  unsigned short* Qr    = (unsigned short*)p; p += (size_t)M * C * 2;
  unsigned short* Kr    = (unsigned short*)p; p += (size_t)M * C * 2;
  unsigned short* Vt    = (unsigned short*)p; p += (size_t)M * C * 2;
  unsigned short* Ob    = xb;  // xb dead after QKV GEMM

  cast_kernel<<<M * C / 1024, 256, 0, stream>>>(x, xb, M * C);
  cast_kernel<<<N1 * C / 1024, 256, 0, stream>>>(Wqkv, wqkvb, N1 * C);
  cast_kernel<<<C * C / 1024, 256, 0, stream>>>(Wout, woutb, C * C);

  gemm256<0><<<dim3((M / 256) * (N1 / 256)), 512, 0, stream>>>(xb, wqkvb, bqkv, qkv, M, N1, C);

  rope_kernel<<<(32 * T * 64) / 256, 256, 0, stream>>>(qkv, Qr, Kr);
  vtrans_kernel<<<dim3(T / 64, 32), 256, 0, stream>>>(qkv, Vt);

  attn_fwd<<<dim3(32, T / 64), 256, 0, stream>>>(Qr, Kr, Vt, Ob, T);

  gemm256<1><<<dim3((M / 256) * (C / 256)), 512, 0, stream>>>(Ob, woutb, bout, out, M, C, C);
}